// Round 4
// baseline (388.682 us; speedup 1.0000x reference)
//
#include <hip/hip_runtime.h>
#include <hip/hip_bf16.h>

#define N_NODES 50000
#define N_EDGES 600000
#define HIDDEN 128

typedef __attribute__((ext_vector_type(8))) short bf16x8;
typedef __attribute__((ext_vector_type(4))) float f32x4;

// f32 -> bf16 round-to-nearest-even (bit trick; inputs are normal randoms)
__device__ __forceinline__ short f2bf(float f) {
    unsigned u = __builtin_bit_cast(unsigned, f);
    u += 0x7fff + ((u >> 16) & 1);
    return (short)(u >> 16);
}

// ---------------------------------------------------------------------------
// Zero the histogram. Own kernel: a graph-captured hipMemsetAsync node costs
// ~180 us per replay (measured round 3); this costs ~3 us.
// ---------------------------------------------------------------------------
__global__ __launch_bounds__(256) void zero_hist_kernel(int* __restrict__ hist, int n)
{
    int i = blockIdx.x * 256 + threadIdx.x;
    if (i < n) hist[i] = 0;
}

// ---------------------------------------------------------------------------
// QKV projection via bf16 MFMA.  out[n,o] = sum_i x[n,i] * W[o,i]  (x @ W^T)
// Block: 512 threads (8 waves), M-tile = 64 nodes, all 3*128 output cols.
// ---------------------------------------------------------------------------
__global__ __launch_bounds__(512, 4) void qkv_mfma_kernel(
    const float* __restrict__ x,
    const float* __restrict__ Wq, const float* __restrict__ Wk,
    const float* __restrict__ Wv,
    float* __restrict__ q, float* __restrict__ k, float* __restrict__ v,
    int n_nodes)
{
    __shared__ bf16x8 xs[1024];  // 64 rows x 16 chunks (16 B each), swizzled

    const int tid   = threadIdx.x;
    const int node0 = blockIdx.x * 64;

    // Stage x tile: 1024 chunks, 2 per thread. Coalesced 32B f32 reads.
    for (int i = 0; i < 2; ++i) {
        int idx = tid + i * 512;
        int row = idx >> 4;
        int ch  = idx & 15;
        int node = node0 + row;
        bf16x8 c = {0, 0, 0, 0, 0, 0, 0, 0};
        if (node < n_nodes) {
            const float* xp = x + (size_t)node * 128 + ch * 8;
            float4 f0 = *reinterpret_cast<const float4*>(xp);
            float4 f1 = *reinterpret_cast<const float4*>(xp + 4);
            c[0] = f2bf(f0.x); c[1] = f2bf(f0.y); c[2] = f2bf(f0.z); c[3] = f2bf(f0.w);
            c[4] = f2bf(f1.x); c[5] = f2bf(f1.y); c[6] = f2bf(f1.z); c[7] = f2bf(f1.w);
        }
        xs[row * 16 + (ch ^ (row & 7))] = c;
    }

    const int wave = tid >> 6;
    const int lane = tid & 63;
    const int ln16 = lane & 15;
    const int kg   = lane >> 4;   // k-subgroup 0..3

    // Load this wave's 3 coltiles of W into registers (bf16 B-fragments).
    bf16x8 wfrag[3][4];
    const int ctbase = wave * 3;
#pragma unroll
    for (int t = 0; t < 3; ++t) {
        int ct = ctbase + t;
        const float* Wm = (ct < 8) ? Wq : (ct < 16 ? Wk : Wv);
        int colbase = (ct & 7) * 16;
        const float* wrow = Wm + (size_t)(colbase + ln16) * 128;
#pragma unroll
        for (int s = 0; s < 4; ++s) {
            const float* wp = wrow + s * 32 + kg * 8;
            float4 f0 = *reinterpret_cast<const float4*>(wp);
            float4 f1 = *reinterpret_cast<const float4*>(wp + 4);
            bf16x8 c;
            c[0] = f2bf(f0.x); c[1] = f2bf(f0.y); c[2] = f2bf(f0.z); c[3] = f2bf(f0.w);
            c[4] = f2bf(f1.x); c[5] = f2bf(f1.y); c[6] = f2bf(f1.z); c[7] = f2bf(f1.w);
            wfrag[t][s] = c;
        }
    }

    __syncthreads();

    // 4 row-groups of 16 rows each; A-fragments reused across 3 coltiles.
    for (int rg = 0; rg < 4; ++rg) {
        bf16x8 afrag[4];
        int row = rg * 16 + ln16;
#pragma unroll
        for (int s = 0; s < 4; ++s) {
            int ch = s * 4 + kg;
            afrag[s] = xs[row * 16 + (ch ^ (row & 7))];
        }
#pragma unroll
        for (int t = 0; t < 3; ++t) {
            f32x4 acc = {0.f, 0.f, 0.f, 0.f};
#pragma unroll
            for (int s = 0; s < 4; ++s)
                acc = __builtin_amdgcn_mfma_f32_16x16x32_bf16(afrag[s], wfrag[t][s], acc, 0, 0, 0);
            int ct = ctbase + t;
            float* outp = (ct < 8) ? q : (ct < 16 ? k : v);
            int colbase = (ct & 7) * 16;
            int rbase = node0 + rg * 16 + kg * 4;
#pragma unroll
            for (int i2 = 0; i2 < 4; ++i2) {
                int node = rbase + i2;
                if (node < n_nodes)
                    outp[(size_t)node * 128 + colbase + ln16] = acc[i2];
            }
        }
    }
}

// ---------------------------------------------------------------------------
// CSR build: histogram -> scan -> slot scatter
// ---------------------------------------------------------------------------
__global__ __launch_bounds__(256) void hist_kernel(
    const int* __restrict__ edge_index, int* __restrict__ hist, int n_edges)
{
    int e = blockIdx.x * 256 + threadIdx.x;
    if (e < n_edges) atomicAdd(&hist[edge_index[n_edges + e]], 1);
}

__global__ __launch_bounds__(1024) void scan_kernel(
    const int* __restrict__ hist, int* __restrict__ offsets,
    int* __restrict__ cursor, int n)
{
    __shared__ int part[1024];
    const int T = 1024;
    const int t = threadIdx.x;
    const int chunk = (n + T - 1) / T;
    const int start = t * chunk;

    int s = 0;
    for (int i = 0; i < chunk; ++i) {
        int idx = start + i;
        if (idx < n) s += hist[idx];
    }
    part[t] = s;
    __syncthreads();
    for (int off = 1; off < T; off <<= 1) {
        int val = 0;
        if (t >= off) val = part[t - off];
        __syncthreads();
        if (t >= off) part[t] += val;
        __syncthreads();
    }
    int run = (t == 0) ? 0 : part[t - 1];
    for (int i = 0; i < chunk; ++i) {
        int idx = start + i;
        if (idx < n) {
            offsets[idx] = run;
            cursor[idx]  = run;
            run += hist[idx];
        }
    }
    if (t == T - 1) offsets[n] = part[T - 1];
}

__global__ __launch_bounds__(256) void scatter_kernel(
    const int* __restrict__ edge_index, const float* __restrict__ cutoff,
    int* __restrict__ cursor, int* __restrict__ csr_src,
    int* __restrict__ csr_eid, float* __restrict__ csr_cut, int n_edges)
{
    int e = blockIdx.x * 256 + threadIdx.x;
    if (e >= n_edges) return;
    int src = edge_index[e];
    int dst = edge_index[n_edges + e];
    int slot = atomicAdd(&cursor[dst], 1);
    csr_src[slot] = src;
    csr_eid[slot] = e;
    csr_cut[slot] = cutoff[e];
}

// ---------------------------------------------------------------------------
// Gather: 32 lanes per node, loop incoming edges, write out once (no atomics).
// ---------------------------------------------------------------------------
__global__ __launch_bounds__(256) void gather_kernel(
    const float* __restrict__ q, const float* __restrict__ k,
    const float* __restrict__ v, const float* __restrict__ w_ij,
    const int* __restrict__ offsets, const int* __restrict__ csr_src,
    const int* __restrict__ csr_eid, const float* __restrict__ csr_cut,
    float* __restrict__ out, int n_nodes)
{
    const int lane = threadIdx.x & 31;
    const int node = blockIdx.x * 8 + (threadIdx.x >> 5);
    if (node >= n_nodes) return;

    const float4 qv = *reinterpret_cast<const float4*>(q + (size_t)node * 128 + lane * 4);
    float4 acc = make_float4(0.f, 0.f, 0.f, 0.f);

    const int beg = offsets[node];
    const int end = offsets[node + 1];

    for (int s = beg; s < end; ++s) {
        const int src  = csr_src[s];
        const int e    = csr_eid[s];
        const float c  = csr_cut[s];
        const float4 wv = *reinterpret_cast<const float4*>(w_ij + (size_t)e * 128 + lane * 4);
        const float4 kv = *reinterpret_cast<const float4*>(k + (size_t)src * 128 + lane * 4);
        const float4 vv = *reinterpret_cast<const float4*>(v + (size_t)src * 128 + lane * 4);

        float sdot = qv.x * wv.x * kv.x + qv.y * wv.y * kv.y +
                     qv.z * wv.z * kv.z + qv.w * wv.w * kv.w;
        sdot += __shfl_xor(sdot, 1);
        sdot += __shfl_xor(sdot, 2);

        const float alpha = sdot * 0.25f * c;  // 1/sqrt(16)=0.25
        acc.x += alpha * vv.x;
        acc.y += alpha * vv.y;
        acc.z += alpha * vv.z;
        acc.w += alpha * vv.w;
    }

    *reinterpret_cast<float4*>(out + (size_t)node * 128 + lane * 4) = acc;
}

extern "C" void kernel_launch(void* const* d_in, const int* in_sizes, int n_in,
                              void* d_out, int out_size, void* d_ws, size_t ws_size,
                              hipStream_t stream) {
    const float* x    = (const float*)d_in[0];
    const float* w_ij = (const float*)d_in[1];
    const int* eidx   = (const int*)d_in[2];
    const float* cut  = (const float*)d_in[3];
    const float* Wq   = (const float*)d_in[4];
    const float* Wk   = (const float*)d_in[5];
    const float* Wv   = (const float*)d_in[6];
    float* out = (float*)d_out;

    const size_t nq = (size_t)N_NODES * HIDDEN;
    float* q = (float*)d_ws;
    float* k = q + nq;
    float* v = k + nq;
    int* hist    = (int*)(v + nq);
    int* offsets = hist + N_NODES;
    int* cursor  = offsets + N_NODES + 1;
    int* csr_src = cursor + N_NODES;
    int* csr_eid = csr_src + N_EDGES;
    float* csr_cut = (float*)(csr_eid + N_EDGES);

    // hist must be zero at the start of every call (atomics accumulate).
    // Own kernel, NOT hipMemsetAsync: a captured memset node costs ~180 us.
    zero_hist_kernel<<<(N_NODES + 255) / 256, 256, 0, stream>>>(hist, N_NODES);

    // QKV projection (MFMA): one kernel computes q, k, v.
    dim3 ggrid((N_NODES + 63) / 64);
    qkv_mfma_kernel<<<ggrid, 512, 0, stream>>>(x, Wq, Wk, Wv, q, k, v, N_NODES);

    // CSR build
    dim3 egrid((N_EDGES + 255) / 256);
    hist_kernel<<<egrid, 256, 0, stream>>>(eidx, hist, N_EDGES);
    scan_kernel<<<1, 1024, 0, stream>>>(hist, offsets, cursor, N_NODES);
    scatter_kernel<<<egrid, 256, 0, stream>>>(eidx, cut, cursor, csr_src,
                                              csr_eid, csr_cut, N_EDGES);

    // Gather (writes every output element exactly once)
    dim3 ngrid((N_NODES + 7) / 8);
    gather_kernel<<<ngrid, 256, 0, stream>>>(q, k, v, w_ij, offsets, csr_src,
                                             csr_eid, csr_cut, out, N_NODES);
}

// Round 5
// 273.527 us; speedup vs baseline: 1.4210x; 1.4210x over previous
//
#include <hip/hip_runtime.h>
#include <hip/hip_bf16.h>

#define N_NODES 50000
#define N_EDGES 600000
#define HIDDEN 128
#define BCAP 64   // bucket capacity per node; Poisson(12) tail @64 ~ 1e-30

typedef __attribute__((ext_vector_type(8))) short bf16x8;
typedef __attribute__((ext_vector_type(4))) float f32x4;

// f32 -> bf16 round-to-nearest-even
__device__ __forceinline__ short f2bf(float f) {
    unsigned u = __builtin_bit_cast(unsigned, f);
    u += 0x7fff + ((u >> 16) & 1);
    return (short)(u >> 16);
}

__global__ __launch_bounds__(256) void zero_kernel(int* __restrict__ p, int n)
{
    int i = blockIdx.x * 256 + threadIdx.x;
    if (i < n) p[i] = 0;
}

// ---------------------------------------------------------------------------
// QKV projection via bf16 MFMA (same structure as round 3; launch_bounds
// relaxed (512,4)->(512,2): VGPR cap 128->256 to rule out scratch spills).
// ---------------------------------------------------------------------------
__global__ __launch_bounds__(512, 2) void qkv_mfma_kernel(
    const float* __restrict__ x,
    const float* __restrict__ Wq, const float* __restrict__ Wk,
    const float* __restrict__ Wv,
    float* __restrict__ q, float* __restrict__ k, float* __restrict__ v,
    int n_nodes)
{
    __shared__ bf16x8 xs[1024];  // 64 rows x 16 chunks (16 B each), swizzled

    const int tid   = threadIdx.x;
    const int node0 = blockIdx.x * 64;

    for (int i = 0; i < 2; ++i) {
        int idx = tid + i * 512;
        int row = idx >> 4;
        int ch  = idx & 15;
        int node = node0 + row;
        bf16x8 c = {0, 0, 0, 0, 0, 0, 0, 0};
        if (node < n_nodes) {
            const float* xp = x + (size_t)node * 128 + ch * 8;
            float4 f0 = *reinterpret_cast<const float4*>(xp);
            float4 f1 = *reinterpret_cast<const float4*>(xp + 4);
            c[0] = f2bf(f0.x); c[1] = f2bf(f0.y); c[2] = f2bf(f0.z); c[3] = f2bf(f0.w);
            c[4] = f2bf(f1.x); c[5] = f2bf(f1.y); c[6] = f2bf(f1.z); c[7] = f2bf(f1.w);
        }
        xs[row * 16 + (ch ^ (row & 7))] = c;
    }

    const int wave = tid >> 6;
    const int lane = tid & 63;
    const int ln16 = lane & 15;
    const int kg   = lane >> 4;

    bf16x8 wfrag[3][4];
    const int ctbase = wave * 3;
#pragma unroll
    for (int t = 0; t < 3; ++t) {
        int ct = ctbase + t;
        const float* Wm = (ct < 8) ? Wq : (ct < 16 ? Wk : Wv);
        int colbase = (ct & 7) * 16;
        const float* wrow = Wm + (size_t)(colbase + ln16) * 128;
#pragma unroll
        for (int s = 0; s < 4; ++s) {
            const float* wp = wrow + s * 32 + kg * 8;
            float4 f0 = *reinterpret_cast<const float4*>(wp);
            float4 f1 = *reinterpret_cast<const float4*>(wp + 4);
            bf16x8 c;
            c[0] = f2bf(f0.x); c[1] = f2bf(f0.y); c[2] = f2bf(f0.z); c[3] = f2bf(f0.w);
            c[4] = f2bf(f1.x); c[5] = f2bf(f1.y); c[6] = f2bf(f1.z); c[7] = f2bf(f1.w);
            wfrag[t][s] = c;
        }
    }

    __syncthreads();

    for (int rg = 0; rg < 4; ++rg) {
        bf16x8 afrag[4];
        int row = rg * 16 + ln16;
#pragma unroll
        for (int s = 0; s < 4; ++s) {
            int ch = s * 4 + kg;
            afrag[s] = xs[row * 16 + (ch ^ (row & 7))];
        }
#pragma unroll
        for (int t = 0; t < 3; ++t) {
            f32x4 acc = {0.f, 0.f, 0.f, 0.f};
#pragma unroll
            for (int s = 0; s < 4; ++s)
                acc = __builtin_amdgcn_mfma_f32_16x16x32_bf16(afrag[s], wfrag[t][s], acc, 0, 0, 0);
            int ct = ctbase + t;
            float* outp = (ct < 8) ? q : (ct < 16 ? k : v);
            int colbase = (ct & 7) * 16;
            int rbase = node0 + rg * 16 + kg * 4;
#pragma unroll
            for (int i2 = 0; i2 < 4; ++i2) {
                int node = rbase + i2;
                if (node < n_nodes)
                    outp[(size_t)node * 128 + colbase + ln16] = acc[i2];
            }
        }
    }
}

// ---------------------------------------------------------------------------
// Bucket build (replaces hist+scan+scatter): one pass, one 8 B store/edge.
// ---------------------------------------------------------------------------
__global__ __launch_bounds__(256) void bucket_kernel(
    const int* __restrict__ edge_index, int* __restrict__ cnt,
    int2* __restrict__ buckets, int n_edges)
{
    int e = blockIdx.x * 256 + threadIdx.x;
    if (e >= n_edges) return;
    int src = edge_index[e];
    int dst = edge_index[n_edges + e];
    int slot = atomicAdd(&cnt[dst], 1);
    if (slot < BCAP)
        buckets[(size_t)dst * BCAP + slot] = make_int2(src, e);
}

// ---------------------------------------------------------------------------
// Edge-parallel alpha: w_ij streamed SEQUENTIALLY (full HBM efficiency);
// q[dst], k[src] gathered (L2/LLC-resident, 25.6 MB each).
// alpha[e][h] = dot(q_i, w_e, k_j)/4 * cutoff[e]
// ---------------------------------------------------------------------------
__global__ __launch_bounds__(256) void alpha_kernel(
    const float* __restrict__ q, const float* __restrict__ k,
    const float* __restrict__ w_ij, const int* __restrict__ edge_index,
    const float* __restrict__ cutoff, float* __restrict__ alpha, int n_edges)
{
    const int lane = threadIdx.x & 31;
    const int e = blockIdx.x * 8 + (threadIdx.x >> 5);
    if (e >= n_edges) return;

    const int src = edge_index[e];
    const int dst = edge_index[n_edges + e];
    const float c = cutoff[e];

    const float4 wv = *reinterpret_cast<const float4*>(w_ij + (size_t)e * 128 + lane * 4);
    const float4 qv = *reinterpret_cast<const float4*>(q + (size_t)dst * 128 + lane * 4);
    const float4 kv = *reinterpret_cast<const float4*>(k + (size_t)src * 128 + lane * 4);

    float s = qv.x * wv.x * kv.x + qv.y * wv.y * kv.y +
              qv.z * wv.z * kv.z + qv.w * wv.w * kv.w;
    s += __shfl_xor(s, 1);
    s += __shfl_xor(s, 2);

    if ((lane & 3) == 0)
        alpha[(size_t)e * 8 + (lane >> 2)] = s * 0.25f * c;
}

// ---------------------------------------------------------------------------
// Node-parallel gather: only alpha (L2) + v (LLC) + bucket entries in the
// loop; depth-1 software pipeline. Writes out exactly once, no atomics.
// ---------------------------------------------------------------------------
__global__ __launch_bounds__(256) void gather_kernel(
    const float* __restrict__ v, const float* __restrict__ alpha,
    const int* __restrict__ cnt, const int2* __restrict__ buckets,
    float* __restrict__ out, int n_nodes)
{
    const int lane = threadIdx.x & 31;
    const int node = blockIdx.x * 8 + (threadIdx.x >> 5);
    if (node >= n_nodes) return;

    const int n = min(cnt[node], BCAP);
    const size_t base = (size_t)node * BCAP;
    const int h = lane >> 2;

    float4 acc = make_float4(0.f, 0.f, 0.f, 0.f);

    int2 e0; float a0 = 0.f; float4 v0 = make_float4(0.f, 0.f, 0.f, 0.f);
    if (n > 0) {
        e0 = buckets[base];
        a0 = alpha[(size_t)e0.y * 8 + h];
        v0 = *reinterpret_cast<const float4*>(v + (size_t)e0.x * 128 + lane * 4);
    }

    for (int s = 0; s < n; ++s) {
        int2 e1; float a1 = 0.f; float4 v1 = make_float4(0.f, 0.f, 0.f, 0.f);
        if (s + 1 < n) {
            e1 = buckets[base + s + 1];
            a1 = alpha[(size_t)e1.y * 8 + h];
            v1 = *reinterpret_cast<const float4*>(v + (size_t)e1.x * 128 + lane * 4);
        }
        acc.x += a0 * v0.x;
        acc.y += a0 * v0.y;
        acc.z += a0 * v0.z;
        acc.w += a0 * v0.w;
        e0 = e1; a0 = a1; v0 = v1;
    }

    *reinterpret_cast<float4*>(out + (size_t)node * 128 + lane * 4) = acc;
}

extern "C" void kernel_launch(void* const* d_in, const int* in_sizes, int n_in,
                              void* d_out, int out_size, void* d_ws, size_t ws_size,
                              hipStream_t stream) {
    const float* x    = (const float*)d_in[0];
    const float* w_ij = (const float*)d_in[1];
    const int* eidx   = (const int*)d_in[2];
    const float* cut  = (const float*)d_in[3];
    const float* Wq   = (const float*)d_in[4];
    const float* Wk   = (const float*)d_in[5];
    const float* Wv   = (const float*)d_in[6];
    float* out = (float*)d_out;

    const size_t nq = (size_t)N_NODES * HIDDEN;
    float* q = (float*)d_ws;
    float* k = q + nq;
    float* v = k + nq;
    int* cnt = (int*)(v + nq);
    int2* buckets = (int2*)(cnt + N_NODES);
    float* alpha = (float*)(buckets + (size_t)N_NODES * BCAP);

    // cnt must be zero at the start of every call (atomics accumulate).
    zero_kernel<<<(N_NODES + 255) / 256, 256, 0, stream>>>(cnt, N_NODES);

    // QKV projection (MFMA)
    dim3 ggrid((N_NODES + 63) / 64);
    qkv_mfma_kernel<<<ggrid, 512, 0, stream>>>(x, Wq, Wk, Wv, q, k, v, N_NODES);

    // Bucket build (single pass)
    dim3 egrid((N_EDGES + 255) / 256);
    bucket_kernel<<<egrid, 256, 0, stream>>>(eidx, cnt, buckets, N_EDGES);

    // Edge-parallel alpha (streams w_ij sequentially)
    dim3 agrid((N_EDGES + 7) / 8);
    alpha_kernel<<<agrid, 256, 0, stream>>>(q, k, w_ij, eidx, cut, alpha, N_EDGES);

    // Node-parallel gather
    dim3 ngrid((N_NODES + 7) / 8);
    gather_kernel<<<ngrid, 256, 0, stream>>>(v, alpha, cnt, buckets, out, N_NODES);
}

// Round 6
// 244.315 us; speedup vs baseline: 1.5909x; 1.1196x over previous
//
#include <hip/hip_runtime.h>
#include <hip/hip_bf16.h>

#define N_NODES 50000
#define N_EDGES 600000
#define HIDDEN 128
#define BCAP 64   // bucket capacity per node; Poisson(12) tail @64 ~ 1e-30

typedef __attribute__((ext_vector_type(8))) short bf16x8;
typedef __attribute__((ext_vector_type(4))) float f32x4;

// f32 -> bf16 round-to-nearest-even
__device__ __forceinline__ short f2bf(float f) {
    unsigned u = __builtin_bit_cast(unsigned, f);
    u += 0x7fff + ((u >> 16) & 1);
    return (short)(u >> 16);
}

// ---------------------------------------------------------------------------
// QKV projection via bf16 MFMA. Also zeroes cnt[] (piggyback: saves a launch;
// edge_kernel only starts after this kernel fully retires).
// ---------------------------------------------------------------------------
__global__ __launch_bounds__(512, 2) void qkv_mfma_kernel(
    const float* __restrict__ x,
    const float* __restrict__ Wq, const float* __restrict__ Wk,
    const float* __restrict__ Wv,
    float* __restrict__ q, float* __restrict__ k, float* __restrict__ v,
    int* __restrict__ cnt, int n_nodes)
{
    __shared__ bf16x8 xs[1024];  // 64 rows x 16 chunks (16 B each), swizzled

    const int tid   = threadIdx.x;
    const int node0 = blockIdx.x * 64;

    // Piggyback: zero the per-node counters.
    {
        int i = blockIdx.x * 512 + tid;
        if (i < n_nodes) cnt[i] = 0;
    }

    for (int i = 0; i < 2; ++i) {
        int idx = tid + i * 512;
        int row = idx >> 4;
        int ch  = idx & 15;
        int node = node0 + row;
        bf16x8 c = {0, 0, 0, 0, 0, 0, 0, 0};
        if (node < n_nodes) {
            const float* xp = x + (size_t)node * 128 + ch * 8;
            float4 f0 = *reinterpret_cast<const float4*>(xp);
            float4 f1 = *reinterpret_cast<const float4*>(xp + 4);
            c[0] = f2bf(f0.x); c[1] = f2bf(f0.y); c[2] = f2bf(f0.z); c[3] = f2bf(f0.w);
            c[4] = f2bf(f1.x); c[5] = f2bf(f1.y); c[6] = f2bf(f1.z); c[7] = f2bf(f1.w);
        }
        xs[row * 16 + (ch ^ (row & 7))] = c;
    }

    const int wave = tid >> 6;
    const int lane = tid & 63;
    const int ln16 = lane & 15;
    const int kg   = lane >> 4;

    bf16x8 wfrag[3][4];
    const int ctbase = wave * 3;
#pragma unroll
    for (int t = 0; t < 3; ++t) {
        int ct = ctbase + t;
        const float* Wm = (ct < 8) ? Wq : (ct < 16 ? Wk : Wv);
        int colbase = (ct & 7) * 16;
        const float* wrow = Wm + (size_t)(colbase + ln16) * 128;
#pragma unroll
        for (int s = 0; s < 4; ++s) {
            const float* wp = wrow + s * 32 + kg * 8;
            float4 f0 = *reinterpret_cast<const float4*>(wp);
            float4 f1 = *reinterpret_cast<const float4*>(wp + 4);
            bf16x8 c;
            c[0] = f2bf(f0.x); c[1] = f2bf(f0.y); c[2] = f2bf(f0.z); c[3] = f2bf(f0.w);
            c[4] = f2bf(f1.x); c[5] = f2bf(f1.y); c[6] = f2bf(f1.z); c[7] = f2bf(f1.w);
            wfrag[t][s] = c;
        }
    }

    __syncthreads();

    for (int rg = 0; rg < 4; ++rg) {
        bf16x8 afrag[4];
        int row = rg * 16 + ln16;
#pragma unroll
        for (int s = 0; s < 4; ++s) {
            int ch = s * 4 + kg;
            afrag[s] = xs[row * 16 + (ch ^ (row & 7))];
        }
#pragma unroll
        for (int t = 0; t < 3; ++t) {
            f32x4 acc = {0.f, 0.f, 0.f, 0.f};
#pragma unroll
            for (int s = 0; s < 4; ++s)
                acc = __builtin_amdgcn_mfma_f32_16x16x32_bf16(afrag[s], wfrag[t][s], acc, 0, 0, 0);
            int ct = ctbase + t;
            float* outp = (ct < 8) ? q : (ct < 16 ? k : v);
            int colbase = (ct & 7) * 16;
            int rbase = node0 + rg * 16 + kg * 4;
#pragma unroll
            for (int i2 = 0; i2 < 4; ++i2) {
                int node = rbase + i2;
                if (node < n_nodes)
                    outp[(size_t)node * 128 + colbase + ln16] = acc[i2];
            }
        }
    }
}

// ---------------------------------------------------------------------------
// Fused edge pass: streams w_ij sequentially (full HBM efficiency), gathers
// q[dst]/k[src] (LLC), computes alpha, allocates the bucket slot, and stores
// src + alpha in SLOT ORDER. Gather then reads contiguously -- no eid
// indirection, no random alpha reads.
// ---------------------------------------------------------------------------
__global__ __launch_bounds__(256) void edge_kernel(
    const float* __restrict__ q, const float* __restrict__ k,
    const float* __restrict__ w_ij, const int* __restrict__ edge_index,
    const float* __restrict__ cutoff, int* __restrict__ cnt,
    int* __restrict__ bsrc, float* __restrict__ balpha, int n_edges)
{
    const int lane = threadIdx.x & 31;
    const int e = blockIdx.x * 8 + (threadIdx.x >> 5);
    if (e >= n_edges) return;

    const int src = edge_index[e];
    const int dst = edge_index[n_edges + e];
    const float c = cutoff[e];

    const float4 wv = *reinterpret_cast<const float4*>(w_ij + (size_t)e * 128 + lane * 4);
    const float4 qv = *reinterpret_cast<const float4*>(q + (size_t)dst * 128 + lane * 4);
    const float4 kv = *reinterpret_cast<const float4*>(k + (size_t)src * 128 + lane * 4);

    float s = qv.x * wv.x * kv.x + qv.y * wv.y * kv.y +
              qv.z * wv.z * kv.z + qv.w * wv.w * kv.w;
    s += __shfl_xor(s, 1);
    s += __shfl_xor(s, 2);

    int slot = 0;
    if (lane == 0) slot = atomicAdd(&cnt[dst], 1);
    slot = __shfl(slot, 0, 32);  // broadcast within this edge's 32-lane group

    if (slot < BCAP) {
        const size_t b = (size_t)dst * BCAP + slot;
        if (lane == 0) bsrc[b] = src;
        if ((lane & 3) == 0)
            balpha[b * 8 + (lane >> 2)] = s * 0.25f * c;  // 1/sqrt(16)=0.25
    }
}

// ---------------------------------------------------------------------------
// Node-parallel gather: contiguous bsrc/balpha reads; v[src] is the only
// random access (LLC-resident). Depth-1 software pipeline; no atomics.
// ---------------------------------------------------------------------------
__global__ __launch_bounds__(256) void gather_kernel(
    const float* __restrict__ v, const int* __restrict__ cnt,
    const int* __restrict__ bsrc, const float* __restrict__ balpha,
    float* __restrict__ out, int n_nodes)
{
    const int lane = threadIdx.x & 31;
    const int node = blockIdx.x * 8 + (threadIdx.x >> 5);
    if (node >= n_nodes) return;

    const int n = min(cnt[node], BCAP);
    const size_t base = (size_t)node * BCAP;
    const int h = lane >> 2;

    float4 acc = make_float4(0.f, 0.f, 0.f, 0.f);

    float a0 = 0.f;
    float4 v0 = make_float4(0.f, 0.f, 0.f, 0.f);
    if (n > 0) {
        int s0 = bsrc[base];
        a0 = balpha[base * 8 + h];
        v0 = *reinterpret_cast<const float4*>(v + (size_t)s0 * 128 + lane * 4);
    }

    for (int s = 0; s < n; ++s) {
        float a1 = 0.f;
        float4 v1 = make_float4(0.f, 0.f, 0.f, 0.f);
        if (s + 1 < n) {
            int s1 = bsrc[base + s + 1];
            a1 = balpha[(base + s + 1) * 8 + h];
            v1 = *reinterpret_cast<const float4*>(v + (size_t)s1 * 128 + lane * 4);
        }
        acc.x += a0 * v0.x;
        acc.y += a0 * v0.y;
        acc.z += a0 * v0.z;
        acc.w += a0 * v0.w;
        a0 = a1; v0 = v1;
    }

    *reinterpret_cast<float4*>(out + (size_t)node * 128 + lane * 4) = acc;
}

extern "C" void kernel_launch(void* const* d_in, const int* in_sizes, int n_in,
                              void* d_out, int out_size, void* d_ws, size_t ws_size,
                              hipStream_t stream) {
    const float* x    = (const float*)d_in[0];
    const float* w_ij = (const float*)d_in[1];
    const int* eidx   = (const int*)d_in[2];
    const float* cut  = (const float*)d_in[3];
    const float* Wq   = (const float*)d_in[4];
    const float* Wk   = (const float*)d_in[5];
    const float* Wv   = (const float*)d_in[6];
    float* out = (float*)d_out;

    const size_t nq = (size_t)N_NODES * HIDDEN;
    float* q = (float*)d_ws;
    float* k = q + nq;
    float* v = k + nq;
    int* cnt = (int*)(v + nq);
    int* bsrc = cnt + N_NODES;
    float* balpha = (float*)(bsrc + (size_t)N_NODES * BCAP);

    // QKV projection (MFMA); also zeroes cnt[] before the edge pass.
    dim3 ggrid((N_NODES + 63) / 64);
    qkv_mfma_kernel<<<ggrid, 512, 0, stream>>>(x, Wq, Wk, Wv, q, k, v, cnt, N_NODES);

    // Fused edge pass: alpha + slot-ordered bucket store.
    dim3 egrid((N_EDGES + 7) / 8);
    edge_kernel<<<egrid, 256, 0, stream>>>(q, k, w_ij, eidx, cut, cnt,
                                           bsrc, balpha, N_EDGES);

    // Node-parallel gather.
    dim3 ngrid((N_NODES + 7) / 8);
    gather_kernel<<<ngrid, 256, 0, stream>>>(v, cnt, bsrc, balpha, out, N_NODES);
}

// Round 7
// 205.723 us; speedup vs baseline: 1.8893x; 1.1876x over previous
//
#include <hip/hip_runtime.h>
#include <hip/hip_bf16.h>

#define N_NODES 50000
#define N_EDGES 600000
#define HIDDEN 128
#define BCAP 64   // bucket capacity per node; Poisson(12) tail @64 ~ 1e-30

typedef __attribute__((ext_vector_type(8))) short bf16x8;
typedef __attribute__((ext_vector_type(4))) short bf16x4;
typedef __attribute__((ext_vector_type(4))) float f32x4;

// f32 -> bf16 round-to-nearest-even
__device__ __forceinline__ short f2bf(float f) {
    unsigned u = __builtin_bit_cast(unsigned, f);
    u += 0x7fff + ((u >> 16) & 1);
    return (short)(u >> 16);
}
__device__ __forceinline__ float bf2f(unsigned short s) {
    unsigned u = ((unsigned)s) << 16;
    return __builtin_bit_cast(float, u);
}

// ---------------------------------------------------------------------------
// QKV projection via bf16 MFMA; outputs stored as bf16 (halves store traffic
// and downstream gather bytes). Also zeroes cnt[] (piggyback).
// ---------------------------------------------------------------------------
__global__ __launch_bounds__(512, 2) void qkv_mfma_kernel(
    const float* __restrict__ x,
    const float* __restrict__ Wq, const float* __restrict__ Wk,
    const float* __restrict__ Wv,
    unsigned short* __restrict__ q, unsigned short* __restrict__ k,
    unsigned short* __restrict__ v,
    int* __restrict__ cnt, int n_nodes)
{
    __shared__ bf16x8 xs[1024];  // 64 rows x 16 chunks (16 B each), swizzled

    const int tid   = threadIdx.x;
    const int node0 = blockIdx.x * 64;

    // Piggyback: zero the per-node counters.
    {
        int i = blockIdx.x * 512 + tid;
        if (i < n_nodes) cnt[i] = 0;
    }

    for (int i = 0; i < 2; ++i) {
        int idx = tid + i * 512;
        int row = idx >> 4;
        int ch  = idx & 15;
        int node = node0 + row;
        bf16x8 c = {0, 0, 0, 0, 0, 0, 0, 0};
        if (node < n_nodes) {
            const float* xp = x + (size_t)node * 128 + ch * 8;
            float4 f0 = *reinterpret_cast<const float4*>(xp);
            float4 f1 = *reinterpret_cast<const float4*>(xp + 4);
            c[0] = f2bf(f0.x); c[1] = f2bf(f0.y); c[2] = f2bf(f0.z); c[3] = f2bf(f0.w);
            c[4] = f2bf(f1.x); c[5] = f2bf(f1.y); c[6] = f2bf(f1.z); c[7] = f2bf(f1.w);
        }
        xs[row * 16 + (ch ^ (row & 7))] = c;
    }

    const int wave = tid >> 6;
    const int lane = tid & 63;
    const int ln16 = lane & 15;
    const int kg   = lane >> 4;

    bf16x8 wfrag[3][4];
    const int ctbase = wave * 3;
#pragma unroll
    for (int t = 0; t < 3; ++t) {
        int ct = ctbase + t;
        const float* Wm = (ct < 8) ? Wq : (ct < 16 ? Wk : Wv);
        int colbase = (ct & 7) * 16;
        const float* wrow = Wm + (size_t)(colbase + ln16) * 128;
#pragma unroll
        for (int s = 0; s < 4; ++s) {
            const float* wp = wrow + s * 32 + kg * 8;
            float4 f0 = *reinterpret_cast<const float4*>(wp);
            float4 f1 = *reinterpret_cast<const float4*>(wp + 4);
            bf16x8 c;
            c[0] = f2bf(f0.x); c[1] = f2bf(f0.y); c[2] = f2bf(f0.z); c[3] = f2bf(f0.w);
            c[4] = f2bf(f1.x); c[5] = f2bf(f1.y); c[6] = f2bf(f1.z); c[7] = f2bf(f1.w);
            wfrag[t][s] = c;
        }
    }

    __syncthreads();

    for (int rg = 0; rg < 4; ++rg) {
        bf16x8 afrag[4];
        int row = rg * 16 + ln16;
#pragma unroll
        for (int s = 0; s < 4; ++s) {
            int ch = s * 4 + kg;
            afrag[s] = xs[row * 16 + (ch ^ (row & 7))];
        }
#pragma unroll
        for (int t = 0; t < 3; ++t) {
            f32x4 acc = {0.f, 0.f, 0.f, 0.f};
#pragma unroll
            for (int s = 0; s < 4; ++s)
                acc = __builtin_amdgcn_mfma_f32_16x16x32_bf16(afrag[s], wfrag[t][s], acc, 0, 0, 0);
            int ct = ctbase + t;
            unsigned short* outp = (ct < 8) ? q : (ct < 16 ? k : v);
            int colbase = (ct & 7) * 16;
            int rbase = node0 + rg * 16 + kg * 4;
#pragma unroll
            for (int i2 = 0; i2 < 4; ++i2) {
                int node = rbase + i2;
                if (node < n_nodes)
                    outp[(size_t)node * 128 + colbase + ln16] =
                        (unsigned short)f2bf(acc[i2]);
            }
        }
    }
}

// ---------------------------------------------------------------------------
// Fused edge pass: streams w_ij sequentially, gathers bf16 q[dst]/k[src]
// (8 B/lane), computes alpha, allocates the bucket slot, stores src + bf16
// alpha in SLOT ORDER.
// ---------------------------------------------------------------------------
__global__ __launch_bounds__(256) void edge_kernel(
    const unsigned short* __restrict__ q, const unsigned short* __restrict__ k,
    const float* __restrict__ w_ij, const int* __restrict__ edge_index,
    const float* __restrict__ cutoff, int* __restrict__ cnt,
    int* __restrict__ bsrc, unsigned short* __restrict__ balpha, int n_edges)
{
    const int lane = threadIdx.x & 31;
    const int e = blockIdx.x * 8 + (threadIdx.x >> 5);
    if (e >= n_edges) return;

    const int src = edge_index[e];
    const int dst = edge_index[n_edges + e];
    const float c = cutoff[e];

    const float4 wv = *reinterpret_cast<const float4*>(w_ij + (size_t)e * 128 + lane * 4);
    const bf16x4 qv = *reinterpret_cast<const bf16x4*>(q + (size_t)dst * 128 + lane * 4);
    const bf16x4 kv = *reinterpret_cast<const bf16x4*>(k + (size_t)src * 128 + lane * 4);

    float s = bf2f((unsigned short)qv[0]) * wv.x * bf2f((unsigned short)kv[0])
            + bf2f((unsigned short)qv[1]) * wv.y * bf2f((unsigned short)kv[1])
            + bf2f((unsigned short)qv[2]) * wv.z * bf2f((unsigned short)kv[2])
            + bf2f((unsigned short)qv[3]) * wv.w * bf2f((unsigned short)kv[3]);
    s += __shfl_xor(s, 1);
    s += __shfl_xor(s, 2);

    int slot = 0;
    if (lane == 0) slot = atomicAdd(&cnt[dst], 1);
    slot = __shfl(slot, 0, 32);  // broadcast within this edge's 32-lane group

    if (slot < BCAP) {
        const size_t b = (size_t)dst * BCAP + slot;
        if (lane == 0) bsrc[b] = src;
        if ((lane & 3) == 0)
            balpha[b * 8 + (lane >> 2)] =
                (unsigned short)f2bf(s * 0.25f * c);  // 1/sqrt(16)=0.25
    }
}

// ---------------------------------------------------------------------------
// Node-parallel gather: one node per WAVE, 2 ways x 32 lanes; each way
// processes every other slot with depth-1 prefetch -> 2x memory-level
// parallelism, half the dependent-chain length. bf16 v rows (256 B).
// ---------------------------------------------------------------------------
__global__ __launch_bounds__(256) void gather_kernel(
    const unsigned short* __restrict__ v, const int* __restrict__ cnt,
    const int* __restrict__ bsrc, const unsigned short* __restrict__ balpha,
    float* __restrict__ out, int n_nodes)
{
    const int lane = threadIdx.x & 63;
    const int l32  = lane & 31;
    const int way  = lane >> 5;
    const int node = blockIdx.x * 4 + (threadIdx.x >> 6);
    if (node >= n_nodes) return;

    const int n = min(cnt[node], BCAP);
    const size_t base = (size_t)node * BCAP;
    const int h = l32 >> 2;

    float4 acc = make_float4(0.f, 0.f, 0.f, 0.f);

    int s = way;
    float a0 = 0.f;
    bf16x4 v0 = {0, 0, 0, 0};
    if (s < n) {
        int sr = bsrc[base + s];
        a0 = bf2f(balpha[(base + s) * 8 + h]);
        v0 = *reinterpret_cast<const bf16x4*>(v + (size_t)sr * 128 + l32 * 4);
    }

    for (; s < n; s += 2) {
        float a1 = 0.f;
        bf16x4 v1 = {0, 0, 0, 0};
        if (s + 2 < n) {
            int sr = bsrc[base + s + 2];
            a1 = bf2f(balpha[(base + s + 2) * 8 + h]);
            v1 = *reinterpret_cast<const bf16x4*>(v + (size_t)sr * 128 + l32 * 4);
        }
        acc.x += a0 * bf2f((unsigned short)v0[0]);
        acc.y += a0 * bf2f((unsigned short)v0[1]);
        acc.z += a0 * bf2f((unsigned short)v0[2]);
        acc.w += a0 * bf2f((unsigned short)v0[3]);
        a0 = a1; v0 = v1;
    }

    // combine the two ways
    acc.x += __shfl_xor(acc.x, 32);
    acc.y += __shfl_xor(acc.y, 32);
    acc.z += __shfl_xor(acc.z, 32);
    acc.w += __shfl_xor(acc.w, 32);

    if (way == 0)
        *reinterpret_cast<float4*>(out + (size_t)node * 128 + l32 * 4) = acc;
}

extern "C" void kernel_launch(void* const* d_in, const int* in_sizes, int n_in,
                              void* d_out, int out_size, void* d_ws, size_t ws_size,
                              hipStream_t stream) {
    const float* x    = (const float*)d_in[0];
    const float* w_ij = (const float*)d_in[1];
    const int* eidx   = (const int*)d_in[2];
    const float* cut  = (const float*)d_in[3];
    const float* Wq   = (const float*)d_in[4];
    const float* Wk   = (const float*)d_in[5];
    const float* Wv   = (const float*)d_in[6];
    float* out = (float*)d_out;

    const size_t nq = (size_t)N_NODES * HIDDEN;
    unsigned short* q = (unsigned short*)d_ws;
    unsigned short* k = q + nq;
    unsigned short* v = k + nq;
    int* cnt = (int*)(v + nq);
    int* bsrc = cnt + N_NODES;
    unsigned short* balpha = (unsigned short*)(bsrc + (size_t)N_NODES * BCAP);

    // QKV projection (MFMA, bf16 out); also zeroes cnt[].
    dim3 ggrid((N_NODES + 63) / 64);
    qkv_mfma_kernel<<<ggrid, 512, 0, stream>>>(x, Wq, Wk, Wv, q, k, v, cnt, N_NODES);

    // Fused edge pass: alpha + slot-ordered bucket store.
    dim3 egrid((N_EDGES + 7) / 8);
    edge_kernel<<<egrid, 256, 0, stream>>>(q, k, w_ij, eidx, cut, cnt,
                                           bsrc, balpha, N_EDGES);

    // Node-parallel gather (one node per wave, 2-way).
    dim3 ngrid((N_NODES + 3) / 4);
    gather_kernel<<<ngrid, 256, 0, stream>>>(v, cnt, bsrc, balpha, out, N_NODES);
}

// Round 8
// 179.066 us; speedup vs baseline: 2.1706x; 1.1489x over previous
//
#include <hip/hip_runtime.h>
#include <hip/hip_bf16.h>

#define N_NODES 50000
#define N_EDGES 600000
#define HIDDEN 128
#define BCAP 64   // bucket capacity per node; Poisson(12) tail @64 ~ 1e-30

typedef __attribute__((ext_vector_type(8))) short bf16x8;
typedef __attribute__((ext_vector_type(4))) short bf16x4;
typedef __attribute__((ext_vector_type(4))) float f32x4;

// f32 -> bf16 round-to-nearest-even
__device__ __forceinline__ short f2bf(float f) {
    unsigned u = __builtin_bit_cast(unsigned, f);
    u += 0x7fff + ((u >> 16) & 1);
    return (short)(u >> 16);
}
__device__ __forceinline__ float bf2f(unsigned short s) {
    unsigned u = ((unsigned)s) << 16;
    return __builtin_bit_cast(float, u);
}

// ---------------------------------------------------------------------------
// QKV projection via bf16 MFMA; outputs stored as bf16. Also zeroes cnt[].
// ---------------------------------------------------------------------------
__global__ __launch_bounds__(512, 2) void qkv_mfma_kernel(
    const float* __restrict__ x,
    const float* __restrict__ Wq, const float* __restrict__ Wk,
    const float* __restrict__ Wv,
    unsigned short* __restrict__ q, unsigned short* __restrict__ k,
    unsigned short* __restrict__ v,
    int* __restrict__ cnt, int n_nodes)
{
    __shared__ bf16x8 xs[1024];  // 64 rows x 16 chunks (16 B each), swizzled

    const int tid   = threadIdx.x;
    const int node0 = blockIdx.x * 64;

    // Piggyback: zero the per-node counters.
    {
        int i = blockIdx.x * 512 + tid;
        if (i < n_nodes) cnt[i] = 0;
    }

    for (int i = 0; i < 2; ++i) {
        int idx = tid + i * 512;
        int row = idx >> 4;
        int ch  = idx & 15;
        int node = node0 + row;
        bf16x8 c = {0, 0, 0, 0, 0, 0, 0, 0};
        if (node < n_nodes) {
            const float* xp = x + (size_t)node * 128 + ch * 8;
            float4 f0 = *reinterpret_cast<const float4*>(xp);
            float4 f1 = *reinterpret_cast<const float4*>(xp + 4);
            c[0] = f2bf(f0.x); c[1] = f2bf(f0.y); c[2] = f2bf(f0.z); c[3] = f2bf(f0.w);
            c[4] = f2bf(f1.x); c[5] = f2bf(f1.y); c[6] = f2bf(f1.z); c[7] = f2bf(f1.w);
        }
        xs[row * 16 + (ch ^ (row & 7))] = c;
    }

    const int wave = tid >> 6;
    const int lane = tid & 63;
    const int ln16 = lane & 15;
    const int kg   = lane >> 4;

    bf16x8 wfrag[3][4];
    const int ctbase = wave * 3;
#pragma unroll
    for (int t = 0; t < 3; ++t) {
        int ct = ctbase + t;
        const float* Wm = (ct < 8) ? Wq : (ct < 16 ? Wk : Wv);
        int colbase = (ct & 7) * 16;
        const float* wrow = Wm + (size_t)(colbase + ln16) * 128;
#pragma unroll
        for (int s = 0; s < 4; ++s) {
            const float* wp = wrow + s * 32 + kg * 8;
            float4 f0 = *reinterpret_cast<const float4*>(wp);
            float4 f1 = *reinterpret_cast<const float4*>(wp + 4);
            bf16x8 c;
            c[0] = f2bf(f0.x); c[1] = f2bf(f0.y); c[2] = f2bf(f0.z); c[3] = f2bf(f0.w);
            c[4] = f2bf(f1.x); c[5] = f2bf(f1.y); c[6] = f2bf(f1.z); c[7] = f2bf(f1.w);
            wfrag[t][s] = c;
        }
    }

    __syncthreads();

    for (int rg = 0; rg < 4; ++rg) {
        bf16x8 afrag[4];
        int row = rg * 16 + ln16;
#pragma unroll
        for (int s = 0; s < 4; ++s) {
            int ch = s * 4 + kg;
            afrag[s] = xs[row * 16 + (ch ^ (row & 7))];
        }
#pragma unroll
        for (int t = 0; t < 3; ++t) {
            f32x4 acc = {0.f, 0.f, 0.f, 0.f};
#pragma unroll
            for (int s = 0; s < 4; ++s)
                acc = __builtin_amdgcn_mfma_f32_16x16x32_bf16(afrag[s], wfrag[t][s], acc, 0, 0, 0);
            int ct = ctbase + t;
            unsigned short* outp = (ct < 8) ? q : (ct < 16 ? k : v);
            int colbase = (ct & 7) * 16;
            int rbase = node0 + rg * 16 + kg * 4;
#pragma unroll
            for (int i2 = 0; i2 < 4; ++i2) {
                int node = rbase + i2;
                if (node < n_nodes)
                    outp[(size_t)node * 128 + colbase + ln16] =
                        (unsigned short)f2bf(acc[i2]);
            }
        }
    }
}

// ---------------------------------------------------------------------------
// Fused edge pass: 16 lanes per edge (lane covers 8 elems -> 4 edges in
// flight per wave, 2x MLP on the random q/k row gathers). Streams w_ij
// sequentially; stores src + bf16 alpha in SLOT ORDER.
// ---------------------------------------------------------------------------
__global__ __launch_bounds__(256) void edge_kernel(
    const unsigned short* __restrict__ q, const unsigned short* __restrict__ k,
    const float* __restrict__ w_ij, const int* __restrict__ edge_index,
    const float* __restrict__ cutoff, int* __restrict__ cnt,
    int* __restrict__ bsrc, unsigned short* __restrict__ balpha, int n_edges)
{
    const int l16 = threadIdx.x & 15;
    const int e = blockIdx.x * 16 + (threadIdx.x >> 4);
    if (e >= n_edges) return;

    const int src = edge_index[e];
    const int dst = edge_index[n_edges + e];
    const float c = cutoff[e];

    const float* wp = w_ij + (size_t)e * 128 + l16 * 8;
    const float4 w0 = *reinterpret_cast<const float4*>(wp);
    const float4 w1 = *reinterpret_cast<const float4*>(wp + 4);
    const bf16x8 qv = *reinterpret_cast<const bf16x8*>(q + (size_t)dst * 128 + l16 * 8);
    const bf16x8 kv = *reinterpret_cast<const bf16x8*>(k + (size_t)src * 128 + l16 * 8);

    float s = bf2f((unsigned short)qv[0]) * w0.x * bf2f((unsigned short)kv[0])
            + bf2f((unsigned short)qv[1]) * w0.y * bf2f((unsigned short)kv[1])
            + bf2f((unsigned short)qv[2]) * w0.z * bf2f((unsigned short)kv[2])
            + bf2f((unsigned short)qv[3]) * w0.w * bf2f((unsigned short)kv[3])
            + bf2f((unsigned short)qv[4]) * w1.x * bf2f((unsigned short)kv[4])
            + bf2f((unsigned short)qv[5]) * w1.y * bf2f((unsigned short)kv[5])
            + bf2f((unsigned short)qv[6]) * w1.z * bf2f((unsigned short)kv[6])
            + bf2f((unsigned short)qv[7]) * w1.w * bf2f((unsigned short)kv[7]);
    // lane pair (2 lanes = 16 elems = one head): head sum
    s += __shfl_xor(s, 1);

    int slot = 0;
    if (l16 == 0) slot = atomicAdd(&cnt[dst], 1);
    slot = __shfl(slot, 0, 16);  // broadcast within this edge's 16-lane group

    if (slot < BCAP) {
        const size_t b = (size_t)dst * BCAP + slot;
        if (l16 == 0) bsrc[b] = src;
        if ((l16 & 1) == 0)
            balpha[b * 8 + (l16 >> 1)] =
                (unsigned short)f2bf(s * 0.25f * c);  // 1/sqrt(16)=0.25
    }
}

// ---------------------------------------------------------------------------
// Node-parallel gather: one node per WAVE, 4 ways x 16 lanes; each way
// processes every 4th slot with depth-1 prefetch -> chain ~deg/4, 4
// independent v[src] streams per wave. bf16 v rows (256 B = 16 x 16 B).
// ---------------------------------------------------------------------------
__global__ __launch_bounds__(256) void gather_kernel(
    const unsigned short* __restrict__ v, const int* __restrict__ cnt,
    const int* __restrict__ bsrc, const unsigned short* __restrict__ balpha,
    float* __restrict__ out, int n_nodes)
{
    const int lane = threadIdx.x & 63;
    const int l16  = lane & 15;
    const int way  = lane >> 4;
    const int node = blockIdx.x * 4 + (threadIdx.x >> 6);
    if (node >= n_nodes) return;

    const int n = min(cnt[node], BCAP);
    const size_t base = (size_t)node * BCAP;
    const int h = l16 >> 1;  // lane covers elems [l16*8, l16*8+8) -> one head

    float acc[8];
#pragma unroll
    for (int j = 0; j < 8; ++j) acc[j] = 0.f;

    int s = way;
    float a0 = 0.f;
    bf16x8 v0 = {0, 0, 0, 0, 0, 0, 0, 0};
    if (s < n) {
        int sr = bsrc[base + s];
        a0 = bf2f(balpha[(base + s) * 8 + h]);
        v0 = *reinterpret_cast<const bf16x8*>(v + (size_t)sr * 128 + l16 * 8);
    }

    for (; s < n; s += 4) {
        float a1 = 0.f;
        bf16x8 v1 = {0, 0, 0, 0, 0, 0, 0, 0};
        if (s + 4 < n) {
            int sr = bsrc[base + s + 4];
            a1 = bf2f(balpha[(base + s + 4) * 8 + h]);
            v1 = *reinterpret_cast<const bf16x8*>(v + (size_t)sr * 128 + l16 * 8);
        }
#pragma unroll
        for (int j = 0; j < 8; ++j)
            acc[j] += a0 * bf2f((unsigned short)v0[j]);
        a0 = a1; v0 = v1;
    }

    // combine the four ways
#pragma unroll
    for (int j = 0; j < 8; ++j) {
        acc[j] += __shfl_xor(acc[j], 16);
        acc[j] += __shfl_xor(acc[j], 32);
    }

    if (way == 0) {
        float* op = out + (size_t)node * 128 + l16 * 8;
        float4 o0 = make_float4(acc[0], acc[1], acc[2], acc[3]);
        float4 o1 = make_float4(acc[4], acc[5], acc[6], acc[7]);
        *reinterpret_cast<float4*>(op)     = o0;
        *reinterpret_cast<float4*>(op + 4) = o1;
    }
}

extern "C" void kernel_launch(void* const* d_in, const int* in_sizes, int n_in,
                              void* d_out, int out_size, void* d_ws, size_t ws_size,
                              hipStream_t stream) {
    const float* x    = (const float*)d_in[0];
    const float* w_ij = (const float*)d_in[1];
    const int* eidx   = (const int*)d_in[2];
    const float* cut  = (const float*)d_in[3];
    const float* Wq   = (const float*)d_in[4];
    const float* Wk   = (const float*)d_in[5];
    const float* Wv   = (const float*)d_in[6];
    float* out = (float*)d_out;

    const size_t nq = (size_t)N_NODES * HIDDEN;
    unsigned short* q = (unsigned short*)d_ws;
    unsigned short* k = q + nq;
    unsigned short* v = k + nq;
    int* cnt = (int*)(v + nq);
    int* bsrc = cnt + N_NODES;
    unsigned short* balpha = (unsigned short*)(bsrc + (size_t)N_NODES * BCAP);

    // QKV projection (MFMA, bf16 out); also zeroes cnt[].
    dim3 ggrid((N_NODES + 63) / 64);
    qkv_mfma_kernel<<<ggrid, 512, 0, stream>>>(x, Wq, Wk, Wv, q, k, v, cnt, N_NODES);

    // Fused edge pass: alpha + slot-ordered bucket store (16 lanes/edge).
    dim3 egrid((N_EDGES + 15) / 16);
    edge_kernel<<<egrid, 256, 0, stream>>>(q, k, w_ij, eidx, cut, cnt,
                                           bsrc, balpha, N_EDGES);

    // Node-parallel gather (one node per wave, 4-way).
    dim3 ngrid((N_NODES + 3) / 4);
    gather_kernel<<<ngrid, 256, 0, stream>>>(v, cnt, bsrc, balpha, out, N_NODES);
}

// Round 9
// 164.087 us; speedup vs baseline: 2.3688x; 1.0913x over previous
//
#include <hip/hip_runtime.h>
#include <hip/hip_bf16.h>

#define N_NODES 50000
#define N_EDGES 600000
#define HIDDEN 128
#define BCAP 64   // bucket capacity per node; Poisson(12) tail @64 ~ 1e-30

typedef __attribute__((ext_vector_type(8))) short bf16x8;
typedef __attribute__((ext_vector_type(4))) short bf16x4;
typedef __attribute__((ext_vector_type(4))) float f32x4;

// f32 -> bf16 round-to-nearest-even
__device__ __forceinline__ short f2bf(float f) {
    unsigned u = __builtin_bit_cast(unsigned, f);
    u += 0x7fff + ((u >> 16) & 1);
    return (short)(u >> 16);
}
__device__ __forceinline__ float bf2f(unsigned short s) {
    unsigned u = ((unsigned)s) << 16;
    return __builtin_bit_cast(float, u);
}

// ---------------------------------------------------------------------------
// W pre-conversion: f32 Wq/Wk/Wv -> bf16 B-fragments in MFMA order.
// wb[((ct*4)+s)*64 + lane], ct = 0..23 (3 matrices x 8 coltiles of 16 cols),
// s = k-step 0..3, lane = MFMA lane. 98 KB total; runs once per launch (~2us).
// ---------------------------------------------------------------------------
__global__ __launch_bounds__(256) void wprep_kernel(
    const float* __restrict__ Wq, const float* __restrict__ Wk,
    const float* __restrict__ Wv, bf16x8* __restrict__ wb)
{
    int t = blockIdx.x * 256 + threadIdx.x;
    if (t >= 24 * 4 * 64) return;
    int ct   = t >> 8;
    int rem  = t & 255;
    int s    = rem >> 6;
    int lane = rem & 63;
    const float* Wm = (ct < 8) ? Wq : (ct < 16 ? Wk : Wv);
    int col = (ct & 7) * 16 + (lane & 15);
    int kb  = s * 32 + (lane >> 4) * 8;
    const float* wp = Wm + (size_t)col * 128 + kb;
    float4 f0 = *reinterpret_cast<const float4*>(wp);
    float4 f1 = *reinterpret_cast<const float4*>(wp + 4);
    bf16x8 c;
    c[0] = f2bf(f0.x); c[1] = f2bf(f0.y); c[2] = f2bf(f0.z); c[3] = f2bf(f0.w);
    c[4] = f2bf(f1.x); c[5] = f2bf(f1.y); c[6] = f2bf(f1.z); c[7] = f2bf(f1.w);
    wb[t] = c;
}

// ---------------------------------------------------------------------------
// QKV projection via bf16 MFMA; M-tile = 128 nodes, 512 threads (8 waves).
// W loaded as prebuilt bf16 fragments (coalesced 1 KB loads, no conversion).
// Outputs stored as bf16. Also zeroes cnt[] (piggyback).
// ---------------------------------------------------------------------------
__global__ __launch_bounds__(512, 2) void qkv_mfma_kernel(
    const float* __restrict__ x, const bf16x8* __restrict__ wb,
    unsigned short* __restrict__ q, unsigned short* __restrict__ k,
    unsigned short* __restrict__ v,
    int* __restrict__ cnt, int n_nodes)
{
    __shared__ bf16x8 xs[2048];  // 128 rows x 16 chunks (16 B each), swizzled

    const int tid   = threadIdx.x;
    const int node0 = blockIdx.x * 128;

    // Piggyback: zero the per-node counters.
    {
        int i = blockIdx.x * 512 + tid;
        if (i < n_nodes) cnt[i] = 0;
    }

    // Stage x tile: 2048 chunks, 4 per thread. Coalesced 32 B f32 reads.
    for (int i = 0; i < 4; ++i) {
        int idx = tid + i * 512;
        int row = idx >> 4;
        int ch  = idx & 15;
        int node = node0 + row;
        bf16x8 c = {0, 0, 0, 0, 0, 0, 0, 0};
        if (node < n_nodes) {
            const float* xp = x + (size_t)node * 128 + ch * 8;
            float4 f0 = *reinterpret_cast<const float4*>(xp);
            float4 f1 = *reinterpret_cast<const float4*>(xp + 4);
            c[0] = f2bf(f0.x); c[1] = f2bf(f0.y); c[2] = f2bf(f0.z); c[3] = f2bf(f0.w);
            c[4] = f2bf(f1.x); c[5] = f2bf(f1.y); c[6] = f2bf(f1.z); c[7] = f2bf(f1.w);
        }
        xs[row * 16 + (ch ^ (row & 7))] = c;
    }

    const int wave = tid >> 6;
    const int lane = tid & 63;
    const int ln16 = lane & 15;
    const int kg   = lane >> 4;

    // Load this wave's 3 coltiles of W fragments (16 B/lane, coalesced).
    bf16x8 wfrag[3][4];
    const int ctbase = wave * 3;
#pragma unroll
    for (int t = 0; t < 3; ++t)
#pragma unroll
        for (int s = 0; s < 4; ++s)
            wfrag[t][s] = wb[(size_t)((ctbase + t) * 4 + s) * 64 + lane];

    __syncthreads();

    for (int rg = 0; rg < 8; ++rg) {
        bf16x8 afrag[4];
        int row = rg * 16 + ln16;
#pragma unroll
        for (int s = 0; s < 4; ++s) {
            int ch = s * 4 + kg;
            afrag[s] = xs[row * 16 + (ch ^ (row & 7))];
        }
#pragma unroll
        for (int t = 0; t < 3; ++t) {
            f32x4 acc = {0.f, 0.f, 0.f, 0.f};
#pragma unroll
            for (int s = 0; s < 4; ++s)
                acc = __builtin_amdgcn_mfma_f32_16x16x32_bf16(afrag[s], wfrag[t][s], acc, 0, 0, 0);
            int ct = ctbase + t;
            unsigned short* outp = (ct < 8) ? q : (ct < 16 ? k : v);
            int colbase = (ct & 7) * 16;
            int rbase = node0 + rg * 16 + kg * 4;
#pragma unroll
            for (int i2 = 0; i2 < 4; ++i2) {
                int node = rbase + i2;
                if (node < n_nodes)
                    outp[(size_t)node * 128 + colbase + ln16] =
                        (unsigned short)f2bf(acc[i2]);
            }
        }
    }
}

// ---------------------------------------------------------------------------
// Fused edge pass: 16 lanes per edge (4 edges in flight per wave). Streams
// w_ij sequentially; stores src + bf16 alpha in SLOT ORDER.
// ---------------------------------------------------------------------------
__global__ __launch_bounds__(256) void edge_kernel(
    const unsigned short* __restrict__ q, const unsigned short* __restrict__ k,
    const float* __restrict__ w_ij, const int* __restrict__ edge_index,
    const float* __restrict__ cutoff, int* __restrict__ cnt,
    int* __restrict__ bsrc, unsigned short* __restrict__ balpha, int n_edges)
{
    const int l16 = threadIdx.x & 15;
    const int e = blockIdx.x * 16 + (threadIdx.x >> 4);
    if (e >= n_edges) return;

    const int src = edge_index[e];
    const int dst = edge_index[n_edges + e];
    const float c = cutoff[e];

    const float* wp = w_ij + (size_t)e * 128 + l16 * 8;
    const float4 w0 = *reinterpret_cast<const float4*>(wp);
    const float4 w1 = *reinterpret_cast<const float4*>(wp + 4);
    const bf16x8 qv = *reinterpret_cast<const bf16x8*>(q + (size_t)dst * 128 + l16 * 8);
    const bf16x8 kv = *reinterpret_cast<const bf16x8*>(k + (size_t)src * 128 + l16 * 8);

    float s = bf2f((unsigned short)qv[0]) * w0.x * bf2f((unsigned short)kv[0])
            + bf2f((unsigned short)qv[1]) * w0.y * bf2f((unsigned short)kv[1])
            + bf2f((unsigned short)qv[2]) * w0.z * bf2f((unsigned short)kv[2])
            + bf2f((unsigned short)qv[3]) * w0.w * bf2f((unsigned short)kv[3])
            + bf2f((unsigned short)qv[4]) * w1.x * bf2f((unsigned short)kv[4])
            + bf2f((unsigned short)qv[5]) * w1.y * bf2f((unsigned short)kv[5])
            + bf2f((unsigned short)qv[6]) * w1.z * bf2f((unsigned short)kv[6])
            + bf2f((unsigned short)qv[7]) * w1.w * bf2f((unsigned short)kv[7]);
    // lane pair (2 lanes = 16 elems = one head): head sum
    s += __shfl_xor(s, 1);

    int slot = 0;
    if (l16 == 0) slot = atomicAdd(&cnt[dst], 1);
    slot = __shfl(slot, 0, 16);  // broadcast within this edge's 16-lane group

    if (slot < BCAP) {
        const size_t b = (size_t)dst * BCAP + slot;
        if (l16 == 0) bsrc[b] = src;
        if ((l16 & 1) == 0)
            balpha[b * 8 + (l16 >> 1)] =
                (unsigned short)f2bf(s * 0.25f * c);  // 1/sqrt(16)=0.25
    }
}

// ---------------------------------------------------------------------------
// Node-parallel gather: one node per WAVE, 4 ways x 16 lanes; each way
// processes every 4th slot with depth-1 prefetch. bf16 v rows (256 B).
// ---------------------------------------------------------------------------
__global__ __launch_bounds__(256) void gather_kernel(
    const unsigned short* __restrict__ v, const int* __restrict__ cnt,
    const int* __restrict__ bsrc, const unsigned short* __restrict__ balpha,
    float* __restrict__ out, int n_nodes)
{
    const int lane = threadIdx.x & 63;
    const int l16  = lane & 15;
    const int way  = lane >> 4;
    const int node = blockIdx.x * 4 + (threadIdx.x >> 6);
    if (node >= n_nodes) return;

    const int n = min(cnt[node], BCAP);
    const size_t base = (size_t)node * BCAP;
    const int h = l16 >> 1;  // lane covers elems [l16*8, l16*8+8) -> one head

    float acc[8];
#pragma unroll
    for (int j = 0; j < 8; ++j) acc[j] = 0.f;

    int s = way;
    float a0 = 0.f;
    bf16x8 v0 = {0, 0, 0, 0, 0, 0, 0, 0};
    if (s < n) {
        int sr = bsrc[base + s];
        a0 = bf2f(balpha[(base + s) * 8 + h]);
        v0 = *reinterpret_cast<const bf16x8*>(v + (size_t)sr * 128 + l16 * 8);
    }

    for (; s < n; s += 4) {
        float a1 = 0.f;
        bf16x8 v1 = {0, 0, 0, 0, 0, 0, 0, 0};
        if (s + 4 < n) {
            int sr = bsrc[base + s + 4];
            a1 = bf2f(balpha[(base + s + 4) * 8 + h]);
            v1 = *reinterpret_cast<const bf16x8*>(v + (size_t)sr * 128 + l16 * 8);
        }
#pragma unroll
        for (int j = 0; j < 8; ++j)
            acc[j] += a0 * bf2f((unsigned short)v0[j]);
        a0 = a1; v0 = v1;
    }

    // combine the four ways
#pragma unroll
    for (int j = 0; j < 8; ++j) {
        acc[j] += __shfl_xor(acc[j], 16);
        acc[j] += __shfl_xor(acc[j], 32);
    }

    if (way == 0) {
        float* op = out + (size_t)node * 128 + l16 * 8;
        float4 o0 = make_float4(acc[0], acc[1], acc[2], acc[3]);
        float4 o1 = make_float4(acc[4], acc[5], acc[6], acc[7]);
        *reinterpret_cast<float4*>(op)     = o0;
        *reinterpret_cast<float4*>(op + 4) = o1;
    }
}

extern "C" void kernel_launch(void* const* d_in, const int* in_sizes, int n_in,
                              void* d_out, int out_size, void* d_ws, size_t ws_size,
                              hipStream_t stream) {
    const float* x    = (const float*)d_in[0];
    const float* w_ij = (const float*)d_in[1];
    const int* eidx   = (const int*)d_in[2];
    const float* cut  = (const float*)d_in[3];
    const float* Wq   = (const float*)d_in[4];
    const float* Wk   = (const float*)d_in[5];
    const float* Wv   = (const float*)d_in[6];
    float* out = (float*)d_out;

    const size_t nq = (size_t)N_NODES * HIDDEN;
    unsigned short* q = (unsigned short*)d_ws;
    unsigned short* k = q + nq;
    unsigned short* v = k + nq;
    int* cnt = (int*)(v + nq);
    int* bsrc = cnt + N_NODES;
    unsigned short* balpha = (unsigned short*)(bsrc + (size_t)N_NODES * BCAP);
    bf16x8* wb = (bf16x8*)(balpha + (size_t)N_NODES * BCAP * 8);

    // W -> bf16 fragment layout (once per launch, ~2 us).
    wprep_kernel<<<24, 256, 0, stream>>>(Wq, Wk, Wv, wb);

    // QKV projection (MFMA, bf16 out, M=128); also zeroes cnt[].
    dim3 ggrid((N_NODES + 127) / 128);
    qkv_mfma_kernel<<<ggrid, 512, 0, stream>>>(x, wb, q, k, v, cnt, N_NODES);

    // Fused edge pass: alpha + slot-ordered bucket store (16 lanes/edge).
    dim3 egrid((N_EDGES + 15) / 16);
    edge_kernel<<<egrid, 256, 0, stream>>>(q, k, w_ij, eidx, cut, cnt,
                                           bsrc, balpha, N_EDGES);

    // Node-parallel gather (one node per wave, 4-way).
    dim3 ngrid((N_NODES + 3) / 4);
    gather_kernel<<<ngrid, 256, 0, stream>>>(v, cnt, bsrc, balpha, out, N_NODES);
}